// Round 7
// baseline (293.321 us; speedup 1.0000x reference)
//
#include <hip/hip_runtime.h>

// TreeAttentionV2: B=8, T=1024, C=1024 (L=4,R=256), H=16, hd=64.
// Pipeline (all fp16 MFMA, fp32 accumulate):
//   1. conv_x:    x fp32 (8192x1024) -> xh fp16
//   2. tconv x2:  w_attn -> waT fp16 (3072x1024), w_proj -> wpT fp16 (1024x1024)
//   3. gemm<split3>: q/k/v = xh @ waT^T + b_attn; Q -> qn natural layout,
//                 K -> kP (MFMA A-fragment order), V -> vP (B-fragment order),
//                 scattered directly in the epilogue (no pack kernels).
//   4. attn v7:   32-row q-tile, 8 waves. Phase1: S^T=K.Q^T, exp->E(LDS, swizzled)
//                 + reg rowsum -> lsum. ONE barrier. Phase2: per-wave 16x16 output
//                 tile over full k=1024, normalize+threshold fused into A-frags,
//                 2-deep acc chain, direct store to y. No reduce, no 2nd barrier.
//   5. gemm<f32>: out = y @ wpT^T + b_proj -> fp32 d_out
//
// Workspace (88 MiB, all live ranges disjoint):
//   [0,16M)   xh   (read by gemm1)
//   [16M,32M) qn   (gemm1 -> attn)
//   [32M,48M) vP   (gemm1 -> attn)
//   [48M,64M) y    (attn -> gemm2)
//   [64M,80M) kP   (gemm1 -> attn)
//   [80M,86M) waT
//   [86M,88M) wpT

typedef _Float16 half8 __attribute__((ext_vector_type(8)));
typedef _Float16 half4_t __attribute__((ext_vector_type(4)));
typedef float floatx4 __attribute__((ext_vector_type(4)));

__device__ __forceinline__ void gl2lds16(const void* gsrc, void* lds) {
    __builtin_amdgcn_global_load_lds(
        (const __attribute__((address_space(1))) unsigned int*)gsrc,
        (__attribute__((address_space(3))) unsigned int*)lds,
        16, 0, 0);
}

// ---------------- elementwise convert fp32 -> fp16 ----------------
__global__ __launch_bounds__(256) void conv_x(const float4* __restrict__ in,
                                              _Float16* __restrict__ out, int n4) {
    int idx = blockIdx.x * blockDim.x + threadIdx.x;
    int stride = gridDim.x * blockDim.x;
    for (int i = idx; i < n4; i += stride) {
        float4 v = in[i];
        half4_t h = { (_Float16)v.x, (_Float16)v.y, (_Float16)v.z, (_Float16)v.w };
        *(half4_t*)(out + (size_t)i * 4) = h;
    }
}

// ------------- transpose + convert: out[n][k] = in[k][n] ----------
__global__ __launch_bounds__(256) void tconv(const float* __restrict__ in,
                                             _Float16* __restrict__ out, int R, int C) {
    __shared__ _Float16 t[64 * 65];
    int bx = blockIdx.x, by = blockIdx.y;
#pragma unroll
    for (int it = 0; it < 16; ++it) {
        int idx = it * 256 + threadIdx.x;
        int r = idx >> 6, c = idx & 63;
        t[c * 65 + r] = (_Float16)in[(size_t)(by * 64 + r) * C + bx * 64 + c];
    }
    __syncthreads();
#pragma unroll
    for (int it = 0; it < 16; ++it) {
        int idx = it * 256 + threadIdx.x;
        int rn = idx >> 6, ck = idx & 63;
        out[(size_t)(bx * 64 + rn) * R + by * 64 + ck] = t[rn * 65 + ck];
    }
}

// ------------- m97-style GEMM: C(MxN) = A(MxK) * BT(NxK)^T + bias -------------
// SPLIT3 (N=3072): sec = n0>>10 (wave-uniform).
//   sec 0 -> qn natural (8192x1024 fp16)
//   sec 1 -> kP fragment order: idx = bh*65536 + (t>>4)*1024 + (d>>5)*512
//                                   + ((d>>3)&3)*128 + (t&15)*8 + (d&7)
//   sec 2 -> vP fragment order: idx = bh*65536 + (t>>5)*2048 + (d>>4)*512
//                                   + ((t>>3)&3)*128 + (d&15)*8 + (t&7)
// else: fp32 out to o0 with row stride N.
template <bool SPLIT3>
__global__ __launch_bounds__(256) void gemm_tn(const _Float16* __restrict__ A,
                                               const _Float16* __restrict__ BT,
                                               const float* __restrict__ bias,
                                               void* __restrict__ o0, void* __restrict__ o1,
                                               void* __restrict__ o2, int N) {
    constexpr int K = 1024;
    __shared__ __attribute__((aligned(16))) _Float16 sA[128 * 32];
    __shared__ __attribute__((aligned(16))) _Float16 sB[128 * 32];
    int tid = threadIdx.x;
    int W = tid >> 6, lane = tid & 63, quad = lane >> 4, l15 = lane & 15;
    int m0 = blockIdx.y * 128, n0 = blockIdx.x * 128;
    int wr = (W >> 1) * 64, wc = (W & 1) * 64;
    floatx4 acc[4][4] = {};

    for (int kt = 0; kt < K / 32; ++kt) {
        int k0 = kt * 32;
#pragma unroll
        for (int rho = 0; rho < 2; ++rho) {
            int lin = rho * 256 + tid;                 // 16B chunk id, tile row-major
            const _Float16* gA = A + (size_t)(m0 + (lin >> 2)) * K + k0 + (lin & 3) * 8;
            const _Float16* gB = BT + (size_t)(n0 + (lin >> 2)) * K + k0 + (lin & 3) * 8;
            int ldsoff = __builtin_amdgcn_readfirstlane((rho * 256 + W * 64) * 16);
            gl2lds16(gA, (char*)sA + ldsoff);
            gl2lds16(gB, (char*)sB + ldsoff);
        }
        __syncthreads();
        half8 a[4], b[4];
#pragma unroll
        for (int rf = 0; rf < 4; ++rf)
            a[rf] = *(const half8*)(sA + (wr + rf * 16 + l15) * 32 + quad * 8);
#pragma unroll
        for (int cf = 0; cf < 4; ++cf)
            b[cf] = *(const half8*)(sB + (wc + cf * 16 + l15) * 32 + quad * 8);
#pragma unroll
        for (int rf = 0; rf < 4; ++rf)
#pragma unroll
            for (int cf = 0; cf < 4; ++cf)
                acc[rf][cf] = __builtin_amdgcn_mfma_f32_16x16x32_f16(a[rf], b[cf], acc[rf][cf], 0, 0, 0);
        __syncthreads();
    }
    int sec = SPLIT3 ? (n0 >> 10) : 0;
#pragma unroll
    for (int cf = 0; cf < 4; ++cf) {
        int gn = n0 + wc + cf * 16 + l15;
        float bv = bias[gn];
        int cn = gn & 1023;
        int hh = cn >> 6, dd = cn & 63;
#pragma unroll
        for (int rf = 0; rf < 4; ++rf) {
            int gmBase = m0 + wr + rf * 16 + quad * 4;
#pragma unroll
            for (int r = 0; r < 4; ++r) {
                float v = acc[rf][cf][r] + bv;
                int gm = gmBase + r;
                if (!SPLIT3) {
                    ((float*)o0)[(size_t)gm * N + gn] = v;
                } else if (sec == 0) {
                    ((_Float16*)o0)[(size_t)gm * 1024 + cn] = (_Float16)v;
                } else {
                    int b = gm >> 10, t = gm & 1023;
                    int bh = b * 16 + hh;
                    if (sec == 1) {
                        size_t idx = (size_t)bh * 65536 + (t >> 4) * 1024 + (dd >> 5) * 512 +
                                     ((dd >> 3) & 3) * 128 + (t & 15) * 8 + (dd & 7);
                        ((_Float16*)o1)[idx] = (_Float16)v;
                    } else {
                        size_t idx = (size_t)bh * 65536 + (t >> 5) * 2048 + (dd >> 4) * 512 +
                                     ((t >> 3) & 3) * 128 + (dd & 15) * 8 + (t & 7);
                        ((_Float16*)o2)[idx] = (_Float16)v;
                    }
                }
            }
        }
    }
}

// ------------------------------- attention v7 -------------------------------
// grid (32 q-tiles of 32 rows, 128 bh), 512 threads = 8 waves.
// Phase1: wave w computes S^T for k in [w*128, w*128+128), exp->E + reg rowsum.
// Phase2: wave w -> output tile (rf = w&1, cf = w>>1) over full k=1024; direct store.
// LDS: E = 32 q-rows x 1024 k fp16 (64KB), xor-swizzled 16B granules; lsum 8x32 f32.
__device__ __forceinline__ int esw(int row, int colByte) {
    return row * 2048 + (colByte ^ ((row & 7) << 4));
}

__global__ __launch_bounds__(512, 4) void attn(const _Float16* __restrict__ qn,
                                               const _Float16* __restrict__ kP,
                                               const _Float16* __restrict__ vP,
                                               _Float16* __restrict__ y) {
    __shared__ __attribute__((aligned(16))) _Float16 E[32 * 1024];
    __shared__ float lsum[8][32];
    char* Eb = (char*)E;
    int tid = threadIdx.x;
    int W = tid >> 6, lane = tid & 63, quad = lane >> 4, l15 = lane & 15;
    int qt = blockIdx.x, bh = blockIdx.y;
    int b = bh >> 4, h = bh & 15;
    int q0 = qt * 32;

    // --- Q as B-fragments (B[k=quad*8+j][n=l15]): n = q-row, k = d ---
    half8 bq[2][2];
#pragma unroll
    for (int nf = 0; nf < 2; ++nf)
#pragma unroll
        for (int ks = 0; ks < 2; ++ks)
            bq[nf][ks] = *(const half8*)(qn + (size_t)(b * 1024 + q0 + nf * 16 + l15) * 1024 +
                                         h * 64 + ks * 32 + quad * 8);

    // --- Phase 1: S^T = K.Q^T (scaled), e = exp(s) -> E; rowsum partials in regs ---
    float lpart[2] = {0.f, 0.f};   // lane's partial rowsum for q = nf*16 + l15
#pragma unroll 4
    for (int mt = 0; mt < 8; ++mt) {
        int kb = W * 8 + mt;
        const _Float16* kp = kP + ((size_t)(bh * 64 + kb) * 128 + lane) * 8;
        half8 ak0 = *(const half8*)(kp);            // contiguous 1KB per wave
        half8 ak1 = *(const half8*)(kp + 512);
#pragma unroll
        for (int nf = 0; nf < 2; ++nf) {
            floatx4 s = {};
            s = __builtin_amdgcn_mfma_f32_16x16x32_f16(ak0, bq[nf][0], s, 0, 0, 0);
            s = __builtin_amdgcn_mfma_f32_16x16x32_f16(ak1, bq[nf][1], s, 0, 0, 0);
            half4_t h4;
#pragma unroll
            for (int r = 0; r < 4; ++r) {
                float e = __expf(fminf(s[r] * 0.125f, 10.0f));  // exp(10)=22026 < fp16 max
                lpart[nf] += e;
                h4[r] = (_Float16)e;
            }
            int q = nf * 16 + l15;
            int kbyte = (W * 128 + mt * 16 + quad * 4) * 2;
            *(half4_t*)(Eb + q * 2048 + (kbyte ^ ((q & 7) << 4))) = h4;
        }
    }
    // reduce over the 4 quads (lanes sharing l15)
#pragma unroll
    for (int nf = 0; nf < 2; ++nf) {
        lpart[nf] += __shfl_xor(lpart[nf], 16);
        lpart[nf] += __shfl_xor(lpart[nf], 32);
    }
    if (lane < 16) {
        lsum[W][l15] = lpart[0];
        lsum[W][16 + l15] = lpart[1];
    }
    __syncthreads();

    // --- Phase 2: per-wave 16x16 output tile over full k; fused normalize+threshold ---
    {
        int rf = W & 1, cf = W >> 1;
        float l = 0.f;
#pragma unroll
        for (int w = 0; w < 8; ++w) l += lsum[w][rf * 16 + l15];
        _Float16 invh = (_Float16)(1.0f / l);
        half8 inv8, t8, z8;
#pragma unroll
        for (int j = 0; j < 8; ++j) { inv8[j] = invh; t8[j] = (_Float16)(-0.001f); z8[j] = (_Float16)0.f; }

        const _Float16* vb = vP + ((size_t)bh * 65536 + cf * 512 + quad * 128 + l15 * 8);
        int erow = rf * 16 + l15;
        floatx4 acc0 = {}, acc1 = {};
#pragma unroll 4
        for (int kt = 0; kt < 32; kt += 2) {
            half8 ap0 = *(const half8*)(Eb + esw(erow, (kt * 32 + quad * 8) * 2));
            half8 bv0 = *(const half8*)(vb + kt * 2048);
            half8 ap1 = *(const half8*)(Eb + esw(erow, ((kt + 1) * 32 + quad * 8) * 2));
            half8 bv1 = *(const half8*)(vb + (kt + 1) * 2048);
            ap0 = __builtin_elementwise_max(ap0 * inv8 + t8, z8);
            ap1 = __builtin_elementwise_max(ap1 * inv8 + t8, z8);
            acc0 = __builtin_amdgcn_mfma_f32_16x16x32_f16(ap0, bv0, acc0, 0, 0, 0);
            acc1 = __builtin_amdgcn_mfma_f32_16x16x32_f16(ap1, bv1, acc1, 0, 0, 0);
        }
        acc0 += acc1;
        // C-layout: col(l15) = d within tile, row(quad*4+r) = q within tile
#pragma unroll
        for (int r = 0; r < 4; ++r) {
            int q = q0 + rf * 16 + quad * 4 + r;
            int d = h * 64 + cf * 16 + l15;
            y[(size_t)(b * 1024 + q) * 1024 + d] = (_Float16)acc0[r];
        }
    }
}

// ------------------------------- launcher -------------------------------
extern "C" void kernel_launch(void* const* d_in, const int* in_sizes, int n_in,
                              void* d_out, int out_size, void* d_ws, size_t ws_size,
                              hipStream_t stream) {
    const float* x  = (const float*)d_in[0];
    const float* wa = (const float*)d_in[1];
    const float* ba = (const float*)d_in[2];
    const float* wp = (const float*)d_in[3];
    const float* bp = (const float*)d_in[4];
    float* out = (float*)d_out;

    char* ws = (char*)d_ws;
    _Float16* xh  = (_Float16*)(ws);                    // [0,16M)
    _Float16* qn  = (_Float16*)(ws + 16777216);         // [16M,32M)
    _Float16* vP  = (_Float16*)(ws + 33554432);         // [32M,48M)
    _Float16* y   = (_Float16*)(ws + 50331648);         // [48M,64M)
    _Float16* kP  = (_Float16*)(ws + 67108864);         // [64M,80M)
    _Float16* waT = (_Float16*)(ws + 83886080);         // [80M,86M)
    _Float16* wpT = (_Float16*)(ws + 90177536);         // [86M,88M)

    conv_x<<<4096, 256, 0, stream>>>((const float4*)x, xh, 8388608 / 4);
    tconv<<<dim3(48, 16), 256, 0, stream>>>(wa, waT, 1024, 3072);
    tconv<<<dim3(16, 16), 256, 0, stream>>>(wp, wpT, 1024, 1024);
    gemm_tn<true><<<dim3(24, 64), 256, 0, stream>>>(xh, waT, ba, (void*)qn, (void*)kP, (void*)vP, 3072);
    attn<<<dim3(32, 128), 512, 0, stream>>>(qn, kP, vP, y);
    gemm_tn<false><<<dim3(8, 64), 256, 0, stream>>>(y, wpT, bp, (void*)out, nullptr, nullptr, 1024);
}